// Round 9
// baseline (301.961 us; speedup 1.0000x reference)
//
#include <hip/hip_runtime.h>

typedef __bf16 bf16;
typedef __bf16 bf16x8 __attribute__((ext_vector_type(8)));
typedef __bf16 bf16x4 __attribute__((ext_vector_type(4)));
typedef float floatx4 __attribute__((ext_vector_type(4)));

#define MFMA_BF16(a, b, c) __builtin_amdgcn_mfma_f32_16x16x32_bf16((a), (b), (c), 0, 0, 0)

// async global->LDS, 16B per lane; LDS dest = wave-uniform base + lane*16
#define GLOAD_LDS16(gp, lp)                                      \
  __builtin_amdgcn_global_load_lds(                              \
      (const __attribute__((address_space(1))) void*)(gp),       \
      (__attribute__((address_space(3))) void*)(lp), 16, 0, 0)

// Problem constants: B=4, T=2048, C=1024, H=16, hd=64; M = B*T = 8192
#define SEQ_T 2048
#define DIM_C 1024
#define HDIM 64
#define MROWS 8192
#define N_QKV 3072

// ---------------- x fp32 -> bf16 ----------------
__global__ __launch_bounds__(256) void f32_to_bf16(
    const float* __restrict__ in, bf16* __restrict__ out) {
  const size_t i = ((size_t)blockIdx.x * 256 + threadIdx.x) * 8;
  const float4 f0 = *(const float4*)&in[i];
  const float4 f1 = *(const float4*)&in[i + 4];
  bf16x8 v;
  v[0] = (bf16)f0.x; v[1] = (bf16)f0.y; v[2] = (bf16)f0.z; v[3] = (bf16)f0.w;
  v[4] = (bf16)f1.x; v[5] = (bf16)f1.y; v[6] = (bf16)f1.z; v[7] = (bf16)f1.w;
  *(bf16x8*)&out[i] = v;
}

// ---------------- transpose fp32 -> bf16: out[N][K] = (bf16)in[K][N] ----------------
__global__ __launch_bounds__(256) void transpose_f32_bf16(
    const float* __restrict__ in, bf16* __restrict__ out, int R, int C) {
  __shared__ bf16 tile[32][33];
  const int bx = blockIdx.x * 32, by = blockIdx.y * 32;
  const int tx = threadIdx.x & 31, ty = threadIdx.x >> 5;
  for (int i = 0; i < 32; i += 8)
    tile[ty + i][tx] = (bf16)in[(size_t)(by + ty + i) * C + bx + tx];
  __syncthreads();
  for (int i = 0; i < 32; i += 8)
    out[(size_t)(bx + ty + i) * R + by + tx] = tile[tx][ty + i];
}

// ---------------- V scale+transpose pre-pass ----------------
// Reads K,V (interleaved qkv), writes VT[bh][d=64][key=2048] with V^T rows
// scaled by 2^(c2*|K-row|^2). Scale math bitwise-identical to original.
__global__ __launch_bounds__(256) void scale_transpose_v(
    const bf16* __restrict__ qkv, bf16* __restrict__ VT) {
  const int bh = blockIdx.x;       // 0..63
  const int kt = blockIdx.y;       // 0..31
  const int bb = bh >> 4, h = bh & 15;
  const int tid = threadIdx.x;
  __shared__ bf16 tile[64][72];    // [d][key ^ (d & 0x38)]
  const int r0 = tid >> 3, c8 = (tid & 7) << 3;
  const float c2 = -0.09016844f;   // -1/16 * log2(e)
  for (int i = 0; i < 2; i++) {
    const int r = r0 + i * 32;
    const size_t gr = (size_t)bb * SEQ_T + kt * 64 + r;
    const bf16x8 kv = *(const bf16x8*)&qkv[gr * N_QKV + 1024 + h * HDIM + c8];
    float s = 0.f;
    for (int j = 0; j < 8; j++) { const float f = (float)kv[j]; s += f * f; }
    s += __shfl_xor(s, 1); s += __shfl_xor(s, 2); s += __shfl_xor(s, 4);
    const float vscale = exp2f(s * c2);
    const bf16x8 vv = *(const bf16x8*)&qkv[gr * N_QKV + 2048 + h * HDIM + c8];
    for (int j = 0; j < 8; j++)
      tile[c8 + j][r ^ c8] = (bf16)((float)vv[j] * vscale);
  }
  __syncthreads();
  for (int i = 0; i < 2; i++) {
    const int u = i * 256 + tid;
    const int d = u >> 3, kc = (u & 7) << 3;
    const bf16x8 ov = *(const bf16x8*)&tile[d][kc ^ (d & 0x38)];
    *(bf16x8*)&VT[(size_t)bh * 131072 + (size_t)d * 2048 + kt * 64 + kc] = ov;
  }
}

// ---------------- GEMM (m97 structure, BK=64): Cout = A @ Bt^T + bias ----------------
template <typename OT>
__global__ __launch_bounds__(256) void gemm_lds(
    const bf16* __restrict__ A,     // M x K row-major (bf16), row stride lda
    const bf16* __restrict__ Bt,    // N x K row-major (bf16)
    const float* __restrict__ bias, // N (fp32)
    OT* __restrict__ Cout,          // M x N row-major
    int M, int N, int K, int lda) {
  __shared__ __align__(16) bf16 Asl[128 * 64];  // seg s: row=s>>3, phys blk=s&7
  __shared__ __align__(16) bf16 Bsl[128 * 64];  // content blk = (s&7) ^ (row&7)
  const int bm = blockIdx.y * 128, bn = blockIdx.x * 128;
  const int tid = threadIdx.x;
  const int wave = tid >> 6, lane = tid & 63;
  const int wm = (wave >> 1) * 64, wn = (wave & 1) * 64;
  const int quad = lane >> 4, l16 = lane & 15;

  const floatx4 zero = {0.f, 0.f, 0.f, 0.f};
  floatx4 acc[4][4];
  for (int i = 0; i < 4; i++)
    for (int j = 0; j < 4; j++) acc[i][j] = zero;

  // per-lane global pointers; seg s = i*256 + tid
  const bf16 *gA[4], *gB[4];
  bf16 *lA[4], *lB[4];
  for (int i = 0; i < 4; i++) {
    const int s = i * 256 + tid;
    const int row = s >> 3;
    const int c = (s & 7) ^ (row & 7);     // content block stored at phys s&7
    gA[i] = &A[(size_t)(bm + row) * lda + c * 8];
    gB[i] = &Bt[(size_t)(bn + row) * K + c * 8];
    lA[i] = &Asl[(i * 256 + wave * 64) * 8];  // wave-uniform bases
    lB[i] = &Bsl[(i * 256 + wave * 64) * 8];
  }

  for (int k0 = 0; k0 < K; k0 += 64) {
    for (int i = 0; i < 4; i++) GLOAD_LDS16(gA[i] + k0, lA[i]);
    for (int i = 0; i < 4; i++) GLOAD_LDS16(gB[i] + k0, lB[i]);
    __syncthreads();
    for (int kk = 0; kk < 2; kk++) {
      bf16x8 af[4], bfr[4];
      for (int it = 0; it < 4; it++) {
        const int row = wm + it * 16 + l16;
        const int phys = (kk * 4 + quad) ^ (row & 7);
        af[it] = *(const bf16x8*)&Asl[row * 64 + phys * 8];
      }
      for (int jt = 0; jt < 4; jt++) {
        const int row = wn + jt * 16 + l16;
        const int phys = (kk * 4 + quad) ^ (row & 7);
        bfr[jt] = *(const bf16x8*)&Bsl[row * 64 + phys * 8];
      }
      for (int it = 0; it < 4; it++)
        for (int jt = 0; jt < 4; jt++)
          acc[it][jt] = MFMA_BF16(af[it], bfr[jt], acc[it][jt]);
    }
    __syncthreads();
  }
  // C/D layout: row = quad*4+reg, col = l16
  for (int jt = 0; jt < 4; jt++) {
    const int col = bn + wn + jt * 16 + l16;
    const float bv = bias[col];
    for (int it = 0; it < 4; it++)
      for (int r = 0; r < 4; r++) {
        const int row = bm + wm + it * 16 + quad * 4 + r;
        Cout[(size_t)row * N + col] = (OT)(acc[it][jt][r] + bv);
      }
  }
}

// ---------------- attention (R8 + exact-40KB LDS -> 4 blocks/CU) ----------------
// R8 showed the tail: 51.7 KB LDS -> 3 blocks/CU resident but grid = 4/CU, so
// each CU runs a serial 4th block at ~1/3 throughput (Occupancy 23.6%).
// This round shrinks LDS to EXACTLY 40960 B (4 x 40960 = 160 KiB):
//  - Ps[128][72] (18.4KB) -> Ps[64*64] (8KB): T-SEQUENTIAL softmax+PV (PV of
//    tile A before softmax of tile B). Safe without barriers: Ps rows are
//    wave-private (row = wave*16+l16 for write and read).
//    Layout: 16B-chunk XOR swizzle keyed by row (chunk ^ (qrow&7)) — the same
//    pattern proven on K/V staging in R8. Writes: 2 lanes/8B slot (floor);
//    reads: full 128B bank spread (floor).
//  - q2c LDS -> sq[2] registers (all lanes hold |q|^2; bitwise-same reduce);
//    epilogue uses __shfl(sq[T], quad*4+r).
// Everything else identical to R8 (passing, absmax 0.03125).
__global__ __launch_bounds__(256, 4) void attn_kernel(
    bf16* __restrict__ qkv,        // 8192 x 3072 : [q | k | y-out]
    const bf16* __restrict__ VT) { // [bh][64 d][2048 key], k2-scaled
  const int p = blockIdx.y;            // 0..15  (paired-triangle pair index)
  const int bh = blockIdx.x;           // 0..63  (XCD-affine: bh%8 pins XCD)
  const int bb = bh >> 4, h = bh & 15;
  const int qtA = p, qtB = 31 - p;
  const int tid = threadIdx.x;
  const int wave = tid >> 6, lane = tid & 63;
  const int quad = lane >> 4, l16 = lane & 15;

  __shared__ __align__(16) bf16 Ps[64 * 64];     // chunk-XOR swizzled, wave-private rows
  __shared__ __align__(16) bf16 Ksl[2][64 * 64]; // [row][phys blk], c = phys ^ (row&7)
  __shared__ __align__(16) bf16 Vsl[2][64 * 64]; // [d][phys blk],   c = phys ^ (d&7)

  const size_t rowbase = (size_t)bb * SEQ_T;
  const float c2 = -0.09016844f;    // -1/16 * log2(e)
  const float m2c2 = 0.18033688f;   // -2*c2

  // ---- Q fragments in registers; every lane keeps c2-scaled |q|^2 input ----
  bf16x8 aq[2][2];
  float sq[2];
  for (int T = 0; T < 2; T++) {
    const int qt = T ? qtB : qtA;
    const size_t grow = rowbase + qt * 64 + wave * 16 + l16;
    float s = 0.f;
    for (int ks = 0; ks < 2; ks++) {
      aq[T][ks] = *(const bf16x8*)&qkv[grow * N_QKV + h * HDIM + ks * 32 + quad * 8];
      for (int j = 0; j < 8; j++) { const float f = (float)aq[T][ks][j]; s += f * f; }
    }
    s += __shfl_xor(s, 16); s += __shfl_xor(s, 32);
    sq[T] = s;                       // identical across quads of an l16 group
  }

  const floatx4 zero = {0.f, 0.f, 0.f, 0.f};
  floatx4 accy[2][4];
  for (int T = 0; T < 2; T++)
    for (int jt = 0; jt < 4; jt++) accy[T][jt] = zero;

  // ---- staging source addresses (XOR-8 swizzled content block) ----
  const int r0 = tid >> 3;                       // row / d (both i share &7)
  const int cb = (tid & 7) ^ (r0 & 7);           // content block
  const bf16* gK = &qkv[(rowbase + r0) * N_QKV + 1024 + h * HDIM + cb * 8];
  const bf16* gV = &VT[(size_t)bh * 131072 + (size_t)r0 * 2048 + cb * 8];

#define STAGE(kt_, nb_) do {                                            \
    const size_t ko = (size_t)(kt_) * 64 * N_QKV;                       \
    const int vo = (kt_) * 64;                                          \
    GLOAD_LDS16(gK + ko,                    &Ksl[nb_][(wave * 64) * 8]);\
    GLOAD_LDS16(gK + ko + (size_t)32 * N_QKV,                           \
                &Ksl[nb_][(256 + wave * 64) * 8]);                      \
    GLOAD_LDS16(gV + vo,                    &Vsl[nb_][(wave * 64) * 8]);\
    GLOAD_LDS16(gV + vo + 32 * 2048,        &Vsl[nb_][(256 + wave * 64) * 8]);\
  } while (0)

  STAGE(0, 0);
  int cur = 0;
  const int qrow = wave * 16 + l16;   // this lane's local q-row (both tiles)
  const int rk = l16 & 7;             // Ps chunk-swizzle key (= qrow & 7)

  for (int kt = 0; kt <= qtB; kt++) {
    const bool actA = (kt <= qtA);
    __syncthreads();   // implicit vmcnt(0): tile kt landed; prev-buf reads done
    if (kt < qtB) STAGE(kt + 1, cur ^ 1);
    const bf16* Kb = Ksl[cur];
    const bf16* Vb = Vsl[cur];

    // ---- K and V fragments (shared by both T) ----
    bf16x8 bk[4][2], bv[4][2];
    for (int jt = 0; jt < 4; jt++)
      for (int ks = 0; ks < 2; ks++) {
        const int phys = (ks * 4 + quad) ^ rk;
        bk[jt][ks] = *(const bf16x8*)&Kb[(jt * 16 + l16) * 64 + phys * 8];
        bv[jt][ks] = *(const bf16x8*)&Vb[(jt * 16 + l16) * 64 + phys * 8];
      }

    // ---- per T (sequential so Ps needs only 64 rows):
    //      S^T = K.Q^T -> P̂ -> Ps -> PV ----
    for (int T = 0; T < 2; T++) {
      if (T == 0 && !actA) continue;
      floatx4 accs[4];
      for (int jt = 0; jt < 4; jt++) accs[jt] = zero;
      for (int ks = 0; ks < 2; ks++)
        for (int jt = 0; jt < 4; jt++)
          accs[jt] = MFMA_BF16(bk[jt][ks], aq[T][ks], accs[jt]);

      // P̂ = 2^(m2c2*qk), diag mask; b64 write at swizzled chunk
      const bool diag = (kt == (T == 0 ? qtA : qtB));
      for (int jt = 0; jt < 4; jt++) {
        const int kb = jt * 16 + quad * 4;
        bf16x4 pw;
        for (int r = 0; r < 4; r++) {
          float pe = exp2f(m2c2 * accs[jt][r]);
          if (diag && kb + r > qrow) pe = 0.f;
          pw[r] = (bf16)pe;
        }
        const int ch = (2 * jt + (quad >> 1)) ^ rk;     // 16B chunk
        *(bf16x4*)&Ps[qrow * 64 + ch * 8 + (quad & 1) * 4] = pw;
      }

      // y += P̂ . Ṽ  (ap read at swizzled chunk)
      for (int ks = 0; ks < 2; ks++) {
        const int ch = (ks * 4 + quad) ^ rk;
        const bf16x8 ap = *(const bf16x8*)&Ps[qrow * 64 + ch * 8];
        for (int jt = 0; jt < 4; jt++)
          accy[T][jt] = MFMA_BF16(ap, bv[jt][ks], accy[T][jt]);
      }
    }
    cur ^= 1;
  }
#undef STAGE

  // ---- epilogue: scale by 2^(c2*q2), store into qkv V-third (stride 3072) ----
  for (int T = 0; T < 2; T++) {
    const int qt = (T == 0) ? qtA : qtB;
    float ysc[4];
    for (int r = 0; r < 4; r++)
      ysc[r] = exp2f(__shfl(sq[T], quad * 4 + r) * c2);
    for (int jt = 0; jt < 4; jt++) {
      const int col = h * HDIM + jt * 16 + l16;
      for (int r = 0; r < 4; r++) {
        const int ml = wave * 16 + quad * 4 + r;
        qkv[(rowbase + qt * 64 + ml) * N_QKV + 2048 + col] =
            (bf16)(accy[T][jt][r] * ysc[r]);
      }
    }
  }
}

extern "C" void kernel_launch(void* const* d_in, const int* in_sizes, int n_in,
                              void* d_out, int out_size, void* d_ws, size_t ws_size,
                              hipStream_t stream) {
  const float* x      = (const float*)d_in[0];  // 8192 x 1024 fp32
  const float* W_attn = (const float*)d_in[1];  // 1024 x 3072 fp32
  const float* b_attn = (const float*)d_in[2];  // 3072 fp32
  const float* W_proj = (const float*)d_in[3];  // 1024 x 1024 fp32
  const float* b_proj = (const float*)d_in[4];  // 1024 fp32
  float* out = (float*)d_out;                   // 8192 x 1024 fp32

  char* ws = (char*)d_ws;
  bf16* qkv = (bf16*)(ws);             // 50,331,648 B  [q|k|v -> q|k|y]
  bf16* VTb = (bf16*)(ws + 50331648);  // 16,777,216 B — holds xb before pre-pass
  bf16* WaT = (bf16*)(ws + 67108864);  //  6,291,456 B
  bf16* WpT = (bf16*)(ws + 73400320);  //  2,097,152 B  (total 75,497,472)
  bf16* xb  = VTb;                     // x-bf16 dead before scale_transpose_v

  f32_to_bf16<<<dim3(4096), 256, 0, stream>>>(x, xb);
  transpose_f32_bf16<<<dim3(96, 32), 256, 0, stream>>>(W_attn, WaT, 1024, 3072);
  transpose_f32_bf16<<<dim3(32, 32), 256, 0, stream>>>(W_proj, WpT, 1024, 1024);
  gemm_lds<bf16><<<dim3(24, 64), 256, 0, stream>>>(
      xb, WaT, b_attn, qkv, MROWS, N_QKV, DIM_C, DIM_C);
  scale_transpose_v<<<dim3(64, 32), 256, 0, stream>>>(qkv, VTb);
  attn_kernel<<<dim3(64, 16), 256, 0, stream>>>(qkv, VTb);
  gemm_lds<float><<<dim3(8, 64), 256, 0, stream>>>(
      qkv + 2048, WpT, b_proj, out, MROWS, DIM_C, DIM_C, N_QKV);
}